// Round 7
// baseline (394.520 us; speedup 1.0000x reference)
//
#include <hip/hip_runtime.h>
#include <hip/hip_bf16.h>

#define BB 16
#define SS 2048
#define DD 64
#define NT (SS / 64)
#define BUFS 20992   // Ks 8192 | Vs 8192 | Ms 4608

typedef __attribute__((ext_vector_type(8)))  unsigned short ushort8;
typedef __attribute__((ext_vector_type(8)))  __bf16 bf16x8;
typedef __attribute__((ext_vector_type(16))) float f32x16;

static __device__ __forceinline__ unsigned short f2bf(float x) {
    return __builtin_bit_cast(unsigned short, __float2bfloat16(x));
}
static __device__ __forceinline__ unsigned pk2f(float a, float b) {
    return (unsigned)f2bf(a) | ((unsigned)f2bf(b) << 16);
}
union F4 { float4 v; float a[4]; };

// bf16 MFMA attention, 32x32x16 tiles (q64/k64, proven r5 core):
// S^T = K*Q^T; P via in-register shfl_xor(32) exchange; O^T = V^T*P^T.
// This round: software pipeline — register prefetch of tile kt+1 overlapped
// with compute of tile kt, LDS double-buffered, ONE barrier per iteration.
// Mask = int32 words (proven r4/r5). No max-subtraction (logits bounded;
// masked -> p = 1.0f exactly, matching exp(1e-9)==1.0f semantics).
__global__ __launch_bounds__(256, 2)
void sdpa_mfma_kernel(const float* __restrict__ Q, const float* __restrict__ K,
                      const float* __restrict__ V, const unsigned int* __restrict__ M,
                      float* __restrict__ O) {
    // smem: [0,8192) Qs ; [8192,+BUFS) buf0 ; [8192+BUFS,+BUFS) buf1
    // epilogue reuse: red = smem+0 (16 KB), denx = smem+16384
    __shared__ __align__(16) char smem[8192 + 2 * BUFS];
    char* Qs = smem;

    const int t    = threadIdx.x;
    const int lane = t & 63;
    const int l31  = lane & 31;
    const int half = lane >> 5;
    const int w    = t >> 6;
    const int qs   = w & 1;    // q-subtile
    const int kh   = w >> 1;   // k-split half
    const int b    = blockIdx.y;
    const int q0   = blockIdx.x * 64;

    const float* Qg = Q + ((size_t)b * SS + q0) * DD;
    const float* Kg = K + (size_t)b * SS * DD;
    const float* Vg = V + (size_t)b * SS * DD;
    const unsigned int* Mg = M + (size_t)b * SS * SS + (size_t)q0 * SS;

    const int sr  = t >> 2;          // Q/mask staging row
    const int scm = t & 3;           // Q/mask staging col group
    const int d0v = (t & 15) * 4;    // V staging cols
    const int kkv = (t >> 4) * 4;    // V staging row base
    const int kr0 = t >> 3;          // K staging row (unit 0; unit 1 = +32)
    const int kg0 = t & 7;           // K staging granule

    // ---- prefetch registers (48 VGPRs) ----
    F4 ka0, ka1, ka2, ka3, va0, va1, va2, va3;
    uint4 ma0, ma1, ma2, ma3;

#define LOAD_TILE(KT) do {                                                     \
        const float* kp_ = Kg + (size_t)(KT) * 64 * DD + 8 * t;                \
        ka0.v = *(const float4*)(kp_);                                         \
        ka1.v = *(const float4*)(kp_ + 4);                                     \
        ka2.v = *(const float4*)(kp_ + 2048);                                  \
        ka3.v = *(const float4*)(kp_ + 2052);                                  \
        const float* vp_ = Vg + (size_t)((KT) * 64 + kkv) * DD + d0v;          \
        va0.v = *(const float4*)(vp_);                                         \
        va1.v = *(const float4*)(vp_ + DD);                                    \
        va2.v = *(const float4*)(vp_ + 2 * DD);                                \
        va3.v = *(const float4*)(vp_ + 3 * DD);                                \
        const unsigned int* mp_ = Mg + (size_t)sr * SS + (KT) * 64 + scm * 16; \
        ma0 = *(const uint4*)(mp_);                                            \
        ma1 = *(const uint4*)(mp_ + 4);                                        \
        ma2 = *(const uint4*)(mp_ + 8);                                        \
        ma3 = *(const uint4*)(mp_ + 12);                                       \
    } while (0)

#define WRITE_TILE(Kp, Vp, Mp) do {                                            \
        ushort8 u_;                                                            \
        _Pragma("unroll")                                                      \
        for (int e = 0; e < 4; e++) { u_[e] = f2bf(ka0.a[e]); u_[e+4] = f2bf(ka1.a[e]); } \
        *(ushort8*)((Kp) + kr0 * 128 + ((kg0 ^ (kr0 & 7)) * 16)) = u_;         \
        _Pragma("unroll")                                                      \
        for (int e = 0; e < 4; e++) { u_[e] = f2bf(ka2.a[e]); u_[e+4] = f2bf(ka3.a[e]); } \
        *(ushort8*)((Kp) + (kr0 + 32) * 128 + ((kg0 ^ (kr0 & 7)) * 16)) = u_;  \
        _Pragma("unroll")                                                      \
        for (int e = 0; e < 4; e++) {                                          \
            const int d_ = d0v + e;                                            \
            *(uint2*)((Vp) + d_ * 128 + (((kkv >> 3) ^ (d_ & 7)) * 16) + (kkv & 7) * 2) \
                = make_uint2(pk2f(va0.a[e], va1.a[e]), pk2f(va2.a[e], va3.a[e])); \
        }                                                                      \
        const unsigned w0_ = (ma0.x?1u:0u)|(ma0.y?0x100u:0u)|(ma0.z?0x10000u:0u)|(ma0.w?0x1000000u:0u); \
        const unsigned w1_ = (ma1.x?1u:0u)|(ma1.y?0x100u:0u)|(ma1.z?0x10000u:0u)|(ma1.w?0x1000000u:0u); \
        const unsigned w2_ = (ma2.x?1u:0u)|(ma2.y?0x100u:0u)|(ma2.z?0x10000u:0u)|(ma2.w?0x1000000u:0u); \
        const unsigned w3_ = (ma3.x?1u:0u)|(ma3.y?0x100u:0u)|(ma3.z?0x10000u:0u)|(ma3.w?0x1000000u:0u); \
        *(uint2*)((Mp) + sr * 72 + scm * 16)     = make_uint2(w0_, w1_);       \
        *(uint2*)((Mp) + sr * 72 + scm * 16 + 8) = make_uint2(w2_, w3_);       \
    } while (0)

    // ---- issue tile-0 prefetch before Q staging (latency head start) ----
    LOAD_TILE(0);

    // ---- stage Q (pre-scaled by 1/temperature), swizzled bf16 ----
    {
        F4 f0, f1, f2, f3;
        const float* src = Qg + sr * DD + scm * 16;
        f0.v = *(const float4*)(src);
        f1.v = *(const float4*)(src + 4);
        f2.v = *(const float4*)(src + 8);
        f3.v = *(const float4*)(src + 12);
        ushort8 u0, u1;
        #pragma unroll
        for (int e = 0; e < 4; e++) {
            u0[e]     = f2bf(f0.a[e] * 0.125f);
            u0[e + 4] = f2bf(f1.a[e] * 0.125f);
            u1[e]     = f2bf(f2.a[e] * 0.125f);
            u1[e + 4] = f2bf(f3.a[e] * 0.125f);
        }
        *(ushort8*)(Qs + sr * 128 + (((scm * 2)     ^ (sr & 7)) * 16)) = u0;
        *(ushort8*)(Qs + sr * 128 + (((scm * 2 + 1) ^ (sr & 7)) * 16)) = u1;
    }
    __syncthreads();

    // ---- preload Q fragments (B operand), registers for whole loop ----
    const int qrow = 32 * qs + l31;
    ushort8 bq[4];
    #pragma unroll
    for (int dc = 0; dc < 4; dc++)
        bq[dc] = *(const ushort8*)(Qs + qrow * 128 + (((2 * dc + half) ^ (qrow & 7)) * 16));

    f32x16 On0, On1;
    #pragma unroll
    for (int i = 0; i < 16; i++) { On0[i] = 0.f; On1[i] = 0.f; }
    float den_acc = 0.f;

    const int krow = 32 * kh + l31;

    for (int kt = 0; kt < NT; ++kt) {
        char* base = smem + 8192 + (kt & 1) * BUFS;
        char* Kp = base;
        char* Vp = base + 8192;
        char* Mp = base + 16384;

        // regs hold tile kt -> LDS[kt&1]; then issue loads for kt+1
        WRITE_TILE(Kp, Vp, Mp);
        if (kt + 1 < NT) LOAD_TILE(kt + 1);
        __syncthreads();   // one barrier per iter: LDS[kt&1] ready

        // ---- QK^T: S^T tile [32k x 32q] ----
        f32x16 S;
        #pragma unroll
        for (int i = 0; i < 16; i++) S[i] = 0.f;
        #pragma unroll
        for (int dc = 0; dc < 4; dc++) {
            bf16x8 ak = __builtin_bit_cast(bf16x8,
                *(const ushort8*)(Kp + krow * 128 + (((2 * dc + half) ^ (krow & 7)) * 16)));
            S = __builtin_amdgcn_mfma_f32_32x32x16_bf16(
                    ak, __builtin_bit_cast(bf16x8, bq[dc]), S, 0, 0, 0);
        }

        // ---- mask + exp + denominator (C row = e + 8g + 4half) ----
        float p[16];
        #pragma unroll
        for (int g = 0; g < 4; g++) {
            const unsigned mw = *(const unsigned*)(Mp + qrow * 72 + 32 * kh + 8 * g + 4 * half);
            #pragma unroll
            for (int e = 0; e < 4; e++) {
                const float ev = __expf(S[4 * g + e]);
                const float pv = ((mw >> (8 * e)) & 0xffu) ? 1.0f : ev;
                p[4 * g + e] = pv;
                den_acc += pv;
            }
        }

        // ---- P·V: B-operand frags via shfl_xor(32) (proven r5), 2 ksubs ----
        #pragma unroll
        for (int s2 = 0; s2 < 2; s2++) {
            const unsigned o0 = pk2f(p[8 * s2 + 0], p[8 * s2 + 1]);
            const unsigned o1 = pk2f(p[8 * s2 + 2], p[8 * s2 + 3]);
            const unsigned o2 = pk2f(p[8 * s2 + 4], p[8 * s2 + 5]);
            const unsigned o3 = pk2f(p[8 * s2 + 6], p[8 * s2 + 7]);
            const unsigned s0 = half ? o0 : o2;
            const unsigned s1 = half ? o1 : o3;
            const unsigned r0 = (unsigned)__shfl_xor((int)s0, 32, 64);
            const unsigned r1 = (unsigned)__shfl_xor((int)s1, 32, 64);
            uint4 bu;
            bu.x = half ? r0 : o0;
            bu.y = half ? r1 : o1;
            bu.z = half ? o2 : r0;
            bu.w = half ? o3 : r1;
            const bf16x8 bp = __builtin_bit_cast(bf16x8, bu);
            #pragma unroll
            for (int dc = 0; dc < 2; dc++) {
                const int vrow = 32 * dc + l31;
                bf16x8 av = __builtin_bit_cast(bf16x8,
                    *(const ushort8*)(Vp + vrow * 128 +
                        (((4 * kh + 2 * s2 + half) ^ (vrow & 7)) * 16)));
                if (dc == 0) On0 = __builtin_amdgcn_mfma_f32_32x32x16_bf16(av, bp, On0, 0, 0, 0);
                else         On1 = __builtin_amdgcn_mfma_f32_32x32x16_bf16(av, bp, On1, 0, 0, 0);
            }
        }
        // no second barrier: next iter writes the OTHER buffer; the single
        // per-iter barrier keeps waves within one iteration of each other.
    }

    // ---- epilogue: lane halves, then the two k-split waves ----
    const float den_tot = den_acc + __shfl_xor(den_acc, 32, 64);
    float* red  = (float*)smem;             // 16 KB over Qs+buf0.K (dead now)
    float* denx = (float*)(smem + 16384);

    __syncthreads();
    if (kh == 1) {
        #pragma unroll
        for (int dc = 0; dc < 2; dc++)
            #pragma unroll
            for (int g = 0; g < 4; g++) {
                const f32x16& Oc = dc ? On1 : On0;
                float4 st;
                st.x = Oc[4 * g + 0]; st.y = Oc[4 * g + 1];
                st.z = Oc[4 * g + 2]; st.w = Oc[4 * g + 3];
                *(float4*)((char*)red + qs * 8192 + (dc * 4 + g) * 1024 + lane * 16) = st;
            }
        if (lane < 32) denx[qs * 32 + l31] = den_tot;
    }
    __syncthreads();
    if (kh == 0) {
        const float inv = 1.0f / (den_tot + denx[qs * 32 + l31]);
        float* Og = O + ((size_t)b * SS + q0 + qrow) * DD;
        #pragma unroll
        for (int dc = 0; dc < 2; dc++)
            #pragma unroll
            for (int g = 0; g < 4; g++) {
                const float4 pr = *(const float4*)((char*)red + qs * 8192 + (dc * 4 + g) * 1024 + lane * 16);
                const f32x16& Oc = dc ? On1 : On0;
                float4 st;
                st.x = (Oc[4 * g + 0] + pr.x) * inv;
                st.y = (Oc[4 * g + 1] + pr.y) * inv;
                st.z = (Oc[4 * g + 2] + pr.z) * inv;
                st.w = (Oc[4 * g + 3] + pr.w) * inv;
                // d = e + 8g + 4half + 32dc  (C-row formula)
                *(float4*)(Og + 32 * dc + 8 * g + 4 * half) = st;
            }
    }
#undef LOAD_TILE
#undef WRITE_TILE
}

extern "C" void kernel_launch(void* const* d_in, const int* in_sizes, int n_in,
                              void* d_out, int out_size, void* d_ws, size_t ws_size,
                              hipStream_t stream) {
    const float* q = (const float*)d_in[0];
    const float* k = (const float*)d_in[1];
    const float* v = (const float*)d_in[2];
    const unsigned int* m = (const unsigned int*)d_in[3];
    float* out = (float*)d_out;

    dim3 grid(SS / 64, BB);   // 32 x 16 = 512 blocks -> exactly 2 per CU, no tail
    sdpa_mfma_kernel<<<grid, 256, 0, stream>>>(q, k, v, m, out);
}